// Round 4
// baseline (474.469 us; speedup 1.0000x reference)
//
#include <hip/hip_runtime.h>
#include <hip/hip_bf16.h>

#define BM 128
#define BN 128
#define BK 32
#define TILE_ELEMS (BM * BK)   // 4096 u16 = 8 KB

typedef __attribute__((ext_vector_type(4))) float floatx4;
typedef __bf16 bf16x8 __attribute__((ext_vector_type(8)));
typedef unsigned int u32;
typedef unsigned short u16;

typedef __attribute__((address_space(1))) const u32 g_u32;
typedef __attribute__((address_space(3))) u32 l_u32;

__device__ __forceinline__ u16 f32_to_bf16(float f) {
    union { float f; u32 u; } x{f};
    u32 u = x.u;
    u32 r = (u + 0x7fffu + ((u >> 16) & 1u)) >> 16;
    return (u16)r;
}

__device__ __forceinline__ float bf16_bits_to_f32(u32 hi_bits) {
    union { u32 u; float f; } x{hi_bits};
    return x.f;
}

// Stage a BM x BK (rows x cols) bf16 tile into LDS via global_load_lds width=16.
// LDS layout: row-major [128][32], contiguous (required by global_load_lds).
__device__ __forceinline__ void stage_tile(const u16* gbase, int ld, u16* lds, int tid) {
#pragma unroll
    for (int it = 0; it < 2; ++it) {
        int flat = it * 2048 + tid * 8;       // element index into 128*32 tile
        int row = flat >> 5;                  // /32
        int col = flat & 31;
        const u16* g = gbase + (long)row * ld + col;
        __builtin_amdgcn_global_load_lds((g_u32*)g, (l_u32*)(&lds[flat]), 16, 0, 0);
    }
}

// C[m0+.., n0+..] = scale * sum_k A[m,k] * B[n,k]  (A,B row-major, K-contiguous)
// Double-buffered LDS: stage(k+1) issued right after the barrier, overlapping
// the ds_read+MFMA of tile k. One barrier per iteration (drains vmcnt+lgkm).
template<bool OUT_BF16>
__device__ __forceinline__ void gemm_body(
    const u16* __restrict__ Ab, const u16* __restrict__ Bb, void* __restrict__ Cb,
    int lda, int ldb, long ldc, int m0, int n0, int nkt, float scale,
    u16* smem)
{
    int tid = threadIdx.x;
    u16* Asb[2] = { smem,                smem + 2 * TILE_ELEMS };
    u16* Bsb[2] = { smem + TILE_ELEMS,   smem + 3 * TILE_ELEMS };

    const u16* Arow = Ab + (long)m0 * lda;
    const u16* Brow = Bb + (long)n0 * ldb;

    stage_tile(Arow, lda, Asb[0], tid);
    stage_tile(Brow, ldb, Bsb[0], tid);

    int wave = tid >> 6, lane = tid & 63;
    int wr = (wave >> 1) * 64, wc = (wave & 1) * 64;
    int lrow = lane & 15, quad = lane >> 4;

    floatx4 acc[4][4] = {};
    const int aoff = (wr + lrow) * BK + quad * 8;
    const int boff = (wc + lrow) * BK + quad * 8;

    for (int kt = 0; kt < nkt; ++kt) {
        __syncthreads();   // drains vmcnt: tile kt is in LDS; prior LDS reads done
        int cur = kt & 1;
        if (kt + 1 < nkt) {   // prefetch next tile into the other buffer NOW
            stage_tile(Arow + (kt + 1) * BK, lda, Asb[cur ^ 1], tid);
            stage_tile(Brow + (kt + 1) * BK, ldb, Bsb[cur ^ 1], tid);
        }
        const u16* As = Asb[cur];
        const u16* Bs = Bsb[cur];
        bf16x8 af[4], bfr[4];
#pragma unroll
        for (int i = 0; i < 4; ++i) {
            af[i]  = *(const bf16x8*)&As[aoff + i * 16 * BK];
            bfr[i] = *(const bf16x8*)&Bs[boff + i * 16 * BK];
        }
#pragma unroll
        for (int mi = 0; mi < 4; ++mi)
#pragma unroll
            for (int ni = 0; ni < 4; ++ni)
                acc[mi][ni] = __builtin_amdgcn_mfma_f32_16x16x32_bf16(af[mi], bfr[ni], acc[mi][ni], 0, 0, 0);
    }

    // Epilogue: C/D layout col = lane&15, row = quad*4 + r
    long crow0 = m0 + wr + quad * 4;
    int  ccol0 = n0 + wc + lrow;
#pragma unroll
    for (int mi = 0; mi < 4; ++mi) {
#pragma unroll
        for (int ni = 0; ni < 4; ++ni) {
#pragma unroll
            for (int r = 0; r < 4; ++r) {
                long row = crow0 + mi * 16 + r;
                long col = ccol0 + ni * 16;
                float v = acc[mi][ni][r] * scale;
                if (OUT_BF16)
                    ((u16*)Cb)[row * ldc + col] = f32_to_bf16(v);
                else
                    ((float*)Cb)[row * ldc + col] = v;
            }
        }
    }
}

// Fused QKV projection: C[16384][3072] = xb[16384][1024] . Wstk[3072][1024]^T
__global__ __launch_bounds__(256)
void qkv_gemm(const u16* __restrict__ A, const u16* __restrict__ B, u16* __restrict__ C)
{
    __shared__ u16 smem[4 * TILE_ELEMS];
    gemm_body<true>(A, B, C, 1024, 1024, 3072,
                    blockIdx.x * BM, blockIdx.y * BN, 32, 1.0f, smem);
}

// S = Q.K^T / sqrt(DK), lower-triangular tiles only (17x8 fold = 136 tiles).
// blockIdx.x = batch -> batch pinned to one XCD.
__global__ __launch_bounds__(256)
void s_gemm(const u16* __restrict__ QKVi, u16* __restrict__ P)
{
    __shared__ u16 smem[4 * TILE_ELEMS];
    int b = blockIdx.x, u = blockIdx.y, v = blockIdx.z;
    int mt, nt;
    if (u <= v) { mt = v; nt = u; } else { mt = 15 - v; nt = u - v - 1; }
    const u16* Ab = QKVi + (long)b * 2048 * 3072;        // Q at col 0
    const u16* Bb = Ab + 1024;                            // K at col 1024
    gemm_body<true>(Ab, Bb, P + (long)b * 2048 * 2048, 3072, 3072, 2048,
                    mt * BM, nt * BN, 32, 0.03125f, smem);
}

// O = P.V with causal K-limit (Keff = m0+128). blockIdx.x = batch -> XCD-pinned.
__global__ __launch_bounds__(256)
void pv_gemm(const u16* __restrict__ P, const u16* __restrict__ Vt, float* __restrict__ O)
{
    __shared__ u16 smem[4 * TILE_ELEMS];
    int b = blockIdx.x, nt = blockIdx.y, mt = blockIdx.z;
    const u16* Ab = P + (long)b * 2048 * 2048;
    const u16* Bb = Vt + (long)b * 2048;                  // ldb = 16384 (all tokens)
    gemm_body<false>(Ab, Bb, O + (long)b * 2048 * 1024, 2048, 16384, 1024,
                     mt * BM, nt * BN, mt * 4 + 4, 1.0f, smem);
}

__global__ __launch_bounds__(256)
void cvt_f32_bf16(const float* __restrict__ src, u16* __restrict__ dst, long n)
{
    long idx = ((long)blockIdx.x * 256 + threadIdx.x) << 2;
    if (idx >= n) return;
    float4 f = *(const float4*)(src + idx);
    ushort4 o;
    o.x = f32_to_bf16(f.x); o.y = f32_to_bf16(f.y);
    o.z = f32_to_bf16(f.z); o.w = f32_to_bf16(f.w);
    *(ushort4*)(dst + idx) = o;
}

// Convert all three weight matrices in one launch.
// 1024 blocks per matrix x 1024 elems per block = 1,048,576 elems each.
__global__ __launch_bounds__(256)
void cvt_w3(const float* __restrict__ Wq, const float* __restrict__ Wk,
            const float* __restrict__ Wv, u16* __restrict__ dst)
{
    int which = blockIdx.x >> 10;                // blocks [0,1024)->Wq, etc.
    const float* src = which == 0 ? Wq : (which == 1 ? Wk : Wv);
    long base = (long)(blockIdx.x & 1023) * 1024 + threadIdx.x * 4;
    float4 f = *(const float4*)(src + base);
    ushort4 o;
    o.x = f32_to_bf16(f.x); o.y = f32_to_bf16(f.y);
    o.z = f32_to_bf16(f.z); o.w = f32_to_bf16(f.w);
    *(ushort4*)(dst + (long)which * 1048576 + base) = o;
}

// Transpose V slice of QKVi (cols 2048..3071) -> Vt[1024][16384], 64x64 LDS tiles.
__global__ __launch_bounds__(256)
void transpose_v(const u16* __restrict__ QKVi, u16* __restrict__ Vt)
{
    __shared__ u16 tile[64][64 + 8];
    int t0 = blockIdx.x * 64;            // token tile (256)
    int d0 = blockIdx.y * 64;            // dv tile (16)
    int tid = threadIdx.x;
    int lr = tid >> 3, lc = (tid & 7) * 8;
#pragma unroll
    for (int p = 0; p < 2; ++p) {
        int tok = lr + p * 32;
        const u16* src = QKVi + (long)(t0 + tok) * 3072 + 2048 + d0 + lc;
        *(uint4*)&tile[tok][lc] = *(const uint4*)src;
    }
    __syncthreads();
#pragma unroll
    for (int p = 0; p < 2; ++p) {
        int dq = lr + p * 32;
        u16 vals[8];
#pragma unroll
        for (int i = 0; i < 8; ++i) vals[i] = tile[lc + i][dq];
        *(uint4*)(Vt + (long)(d0 + dq) * 16384 + t0 + lc) = *(const uint4*)vals;
    }
}

// One block per row: causal softmax over j<=i, in place on P (bf16).
__global__ __launch_bounds__(256)
void softmax_causal(u16* __restrict__ P)
{
    __shared__ float red[8];
    long rowg = blockIdx.x;              // 0 .. B*N-1
    int i = (int)(rowg & 2047);
    u16* prow = P + (rowg << 11);        // row stride N=2048
    int tid = threadIdx.x;
    int j0 = tid << 3;

    uint4 rv = *(const uint4*)(prow + j0);
    u32 w[4] = {rv.x, rv.y, rv.z, rv.w};
    float x[8];
#pragma unroll
    for (int t = 0; t < 4; ++t) {
        x[2 * t]     = bf16_bits_to_f32(w[t] << 16);
        x[2 * t + 1] = bf16_bits_to_f32(w[t] & 0xffff0000u);
    }
#pragma unroll
    for (int e = 0; e < 8; ++e)
        if (j0 + e > i) x[e] = -1e30f;

    float m = x[0];
#pragma unroll
    for (int e = 1; e < 8; ++e) m = fmaxf(m, x[e]);
#pragma unroll
    for (int o = 32; o; o >>= 1) m = fmaxf(m, __shfl_xor(m, o, 64));
    if ((tid & 63) == 0) red[tid >> 6] = m;
    __syncthreads();
    m = fmaxf(fmaxf(red[0], red[1]), fmaxf(red[2], red[3]));

    float e8[8], s = 0.f;
#pragma unroll
    for (int e = 0; e < 8; ++e) { e8[e] = __expf(x[e] - m); s += e8[e]; }
#pragma unroll
    for (int o = 32; o; o >>= 1) s += __shfl_xor(s, o, 64);
    if ((tid & 63) == 0) red[4 + (tid >> 6)] = s;
    __syncthreads();
    s = red[4] + red[5] + red[6] + red[7];
    float inv = 1.0f / s;

    u32 outw[4];
#pragma unroll
    for (int t = 0; t < 4; ++t) {
        u32 lo = f32_to_bf16(e8[2 * t] * inv);
        u32 hi = f32_to_bf16(e8[2 * t + 1] * inv);
        outw[t] = lo | (hi << 16);
    }
    uint4 ov; ov.x = outw[0]; ov.y = outw[1]; ov.z = outw[2]; ov.w = outw[3];
    *(uint4*)(prow + j0) = ov;
}

extern "C" void kernel_launch(void* const* d_in, const int* in_sizes, int n_in,
                              void* d_out, int out_size, void* d_ws, size_t ws_size,
                              hipStream_t stream)
{
    const int B = 8, N = 2048, D = 1024;
    const long MT = (long)B * N;          // 16384
    const long nX = MT * D;               // 16,777,216
    const long nW = (long)D * D;          // 1,048,576

    const float* x  = (const float*)d_in[0];
    const float* Wq = (const float*)d_in[1];
    const float* Wk = (const float*)d_in[2];
    const float* Wv = (const float*)d_in[3];
    float* out = (float*)d_out;

    // ws layout:
    u16* wb   = (u16*)d_ws;        // [3072][1024] stacked Wq;Wk;Wv
    u16* xb   = wb + 3 * nW;       // [16384][1024]; reused as Vt after QKV gemm
    u16* QKVi = xb + nX;           // [16384][3072] interleaved Q|K|V
    u16* P    = QKVi + 3 * nX;     // [8][2048][2048]
    u16* Vt   = xb;                // alias: [1024][16384]

    // 1) fp32 -> bf16
    cvt_f32_bf16<<<(int)(nX / 1024), 256, 0, stream>>>(x, xb, nX);
    cvt_w3<<<3072, 256, 0, stream>>>(Wq, Wk, Wv, wb);

    // 2) fused QKV projection
    qkv_gemm<<<dim3(128, 24, 1), 256, 0, stream>>>(xb, wb, QKVi);

    // 3) V -> Vt (overwrites xb, which is now dead)
    transpose_v<<<dim3(256, 16, 1), 256, 0, stream>>>(QKVi, Vt);

    // 4) S = Q.K^T * 1/32, triangular tiles only, batch -> XCD
    s_gemm<<<dim3(8, 17, 8), 256, 0, stream>>>(QKVi, P);

    // 5) causal softmax in place
    softmax_causal<<<(int)MT, 256, 0, stream>>>(P);

    // 6) O = P.V, K-limited, batch -> XCD
    pv_gemm<<<dim3(8, 8, 16), 256, 0, stream>>>(P, Vt, out);
}

// Round 5
// 422.117 us; speedup vs baseline: 1.1240x; 1.1240x over previous
//
#include <hip/hip_runtime.h>
#include <hip/hip_bf16.h>

#define BM 128
#define BN 128
#define BK 32
#define TILE_ELEMS (BM * BK)   // 4096 u16 = 8 KB

typedef __attribute__((ext_vector_type(4))) float floatx4;
typedef __bf16 bf16x8 __attribute__((ext_vector_type(8)));
typedef unsigned int u32;
typedef unsigned short u16;

typedef __attribute__((address_space(1))) const u32 g_u32;
typedef __attribute__((address_space(3))) u32 l_u32;

__device__ __forceinline__ u16 f32_to_bf16(float f) {
    union { float f; u32 u; } x{f};
    u32 u = x.u;
    u32 r = (u + 0x7fffu + ((u >> 16) & 1u)) >> 16;
    return (u16)r;
}

__device__ __forceinline__ float bf16_bits_to_f32(u32 hi_bits) {
    union { u32 u; float f; } x{hi_bits};
    return x.f;
}

// Stage a BM x BK (rows x cols) bf16 tile into LDS via global_load_lds width=16.
// LDS layout: row-major [128][32], contiguous (required by global_load_lds).
__device__ __forceinline__ void stage_tile(const u16* gbase, int ld, u16* lds, int tid) {
#pragma unroll
    for (int it = 0; it < 2; ++it) {
        int flat = it * 2048 + tid * 8;       // element index into 128*32 tile
        int row = flat >> 5;                  // /32
        int col = flat & 31;
        const u16* g = gbase + (long)row * ld + col;
        __builtin_amdgcn_global_load_lds((g_u32*)g, (l_u32*)(&lds[flat]), 16, 0, 0);
    }
}

// ROUND-2 STRUCTURE (reverted from dbuf — dbuf measured 194us vs 145us):
// sync -> ds_read -> MFMA -> sync -> stage(k+1). Single 16KB buffer pair.
template<bool OUT_BF16>
__device__ __forceinline__ void gemm_body(
    const u16* __restrict__ Ab, const u16* __restrict__ Bb, void* __restrict__ Cb,
    int lda, int ldb, long ldc, int m0, int n0, int nkt, float scale,
    u16* As, u16* Bs)
{
    int tid = threadIdx.x;

    const u16* Arow = Ab + (long)m0 * lda;
    const u16* Brow = Bb + (long)n0 * ldb;

    stage_tile(Arow, lda, As, tid);
    stage_tile(Brow, ldb, Bs, tid);

    int wave = tid >> 6, lane = tid & 63;
    int wr = (wave >> 1) * 64, wc = (wave & 1) * 64;
    int lrow = lane & 15, quad = lane >> 4;

    floatx4 acc[4][4] = {};
    const int aoff = (wr + lrow) * BK + quad * 8;
    const int boff = (wc + lrow) * BK + quad * 8;

    for (int kt = 0; kt < nkt; ++kt) {
        __syncthreads();   // drains vmcnt: staged tile is in LDS
        bf16x8 af[4], bfr[4];
#pragma unroll
        for (int i = 0; i < 4; ++i) {
            af[i]  = *(const bf16x8*)&As[aoff + i * 16 * BK];
            bfr[i] = *(const bf16x8*)&Bs[boff + i * 16 * BK];
        }
#pragma unroll
        for (int mi = 0; mi < 4; ++mi)
#pragma unroll
            for (int ni = 0; ni < 4; ++ni)
                acc[mi][ni] = __builtin_amdgcn_mfma_f32_16x16x32_bf16(af[mi], bfr[ni], acc[mi][ni], 0, 0, 0);
        __syncthreads();   // all reads done before restage
        if (kt + 1 < nkt) {
            stage_tile(Arow + (kt + 1) * BK, lda, As, tid);
            stage_tile(Brow + (kt + 1) * BK, ldb, Bs, tid);
        }
    }

    // Epilogue: C/D layout col = lane&15, row = quad*4 + r
    long crow0 = m0 + wr + quad * 4;
    int  ccol0 = n0 + wc + lrow;
#pragma unroll
    for (int mi = 0; mi < 4; ++mi) {
#pragma unroll
        for (int ni = 0; ni < 4; ++ni) {
#pragma unroll
            for (int r = 0; r < 4; ++r) {
                long row = crow0 + mi * 16 + r;
                long col = ccol0 + ni * 16;
                float v = acc[mi][ni][r] * scale;
                if (OUT_BF16)
                    ((u16*)Cb)[row * ldc + col] = f32_to_bf16(v);
                else
                    ((float*)Cb)[row * ldc + col] = v;
            }
        }
    }
}

// Fused QKV projection: C[16384][3072] = xb[16384][1024] . Wstk[3072][1024]^T
// XCD swizzle: grid (8,384); xcd = blockIdx.x owns contiguous M-slab of 16 tiles
// (4 MB A — fits one XCD L2, reused across all 24 n-tiles; B streams).
__global__ __launch_bounds__(256)
void qkv_gemm(const u16* __restrict__ A, const u16* __restrict__ B, u16* __restrict__ C)
{
    __shared__ u16 As[TILE_ELEMS];
    __shared__ u16 Bs[TILE_ELEMS];
    int xcd = blockIdx.x, i = blockIdx.y;
    int mt = xcd * 16 + (i & 15);
    int nt = i >> 4;
    gemm_body<true>(A, B, C, 1024, 1024, 3072,
                    mt * BM, nt * BN, 32, 1.0f, As, Bs);
}

// S = Q.K^T / sqrt(DK), lower-triangular tiles only (17x8 fold = 136 tiles).
// blockIdx.x = batch -> batch pinned to one XCD.
__global__ __launch_bounds__(256)
void s_gemm(const u16* __restrict__ QKVi, u16* __restrict__ P)
{
    __shared__ u16 As[TILE_ELEMS];
    __shared__ u16 Bs[TILE_ELEMS];
    int b = blockIdx.x, u = blockIdx.y, v = blockIdx.z;
    int mt, nt;
    if (u <= v) { mt = v; nt = u; } else { mt = 15 - v; nt = u - v - 1; }
    const u16* Ab = QKVi + (long)b * 2048 * 3072;        // Q at col 0
    const u16* Bb = Ab + 1024;                            // K at col 1024
    gemm_body<true>(Ab, Bb, P + (long)b * 2048 * 2048, 3072, 3072, 2048,
                    mt * BM, nt * BN, 32, 0.03125f, As, Bs);
}

// O = P.V with causal K-limit (Keff = m0+128). blockIdx.x = batch -> XCD-pinned.
__global__ __launch_bounds__(256)
void pv_gemm(const u16* __restrict__ P, const u16* __restrict__ Vt, float* __restrict__ O)
{
    __shared__ u16 As[TILE_ELEMS];
    __shared__ u16 Bs[TILE_ELEMS];
    int b = blockIdx.x, nt = blockIdx.y, mt = blockIdx.z;
    const u16* Ab = P + (long)b * 2048 * 2048;
    const u16* Bb = Vt + (long)b * 2048;                  // ldb = 16384 (all tokens)
    gemm_body<false>(Ab, Bb, O + (long)b * 2048 * 1024, 2048, 16384, 1024,
                     mt * BM, nt * BN, mt * 4 + 4, 1.0f, As, Bs);
}

__global__ __launch_bounds__(256)
void cvt_f32_bf16(const float* __restrict__ src, u16* __restrict__ dst, long n)
{
    long idx = ((long)blockIdx.x * 256 + threadIdx.x) << 2;
    if (idx >= n) return;
    float4 f = *(const float4*)(src + idx);
    ushort4 o;
    o.x = f32_to_bf16(f.x); o.y = f32_to_bf16(f.y);
    o.z = f32_to_bf16(f.z); o.w = f32_to_bf16(f.w);
    *(ushort4*)(dst + idx) = o;
}

// Convert all three weight matrices in one launch.
// 1024 blocks per matrix x 1024 elems per block = 1,048,576 elems each.
__global__ __launch_bounds__(256)
void cvt_w3(const float* __restrict__ Wq, const float* __restrict__ Wk,
            const float* __restrict__ Wv, u16* __restrict__ dst)
{
    int which = blockIdx.x >> 10;                // blocks [0,1024)->Wq, etc.
    const float* src = which == 0 ? Wq : (which == 1 ? Wk : Wv);
    long base = (long)(blockIdx.x & 1023) * 1024 + threadIdx.x * 4;
    float4 f = *(const float4*)(src + base);
    ushort4 o;
    o.x = f32_to_bf16(f.x); o.y = f32_to_bf16(f.y);
    o.z = f32_to_bf16(f.z); o.w = f32_to_bf16(f.w);
    *(ushort4*)(dst + (long)which * 1048576 + base) = o;
}

// Transpose V slice of QKVi (cols 2048..3071) -> Vt[1024][16384], 64x64 LDS tiles.
__global__ __launch_bounds__(256)
void transpose_v(const u16* __restrict__ QKVi, u16* __restrict__ Vt)
{
    __shared__ u16 tile[64][64 + 8];
    int t0 = blockIdx.x * 64;            // token tile (256)
    int d0 = blockIdx.y * 64;            // dv tile (16)
    int tid = threadIdx.x;
    int lr = tid >> 3, lc = (tid & 7) * 8;
#pragma unroll
    for (int p = 0; p < 2; ++p) {
        int tok = lr + p * 32;
        const u16* src = QKVi + (long)(t0 + tok) * 3072 + 2048 + d0 + lc;
        *(uint4*)&tile[tok][lc] = *(const uint4*)src;
    }
    __syncthreads();
#pragma unroll
    for (int p = 0; p < 2; ++p) {
        int dq = lr + p * 32;
        u16 vals[8];
#pragma unroll
        for (int i = 0; i < 8; ++i) vals[i] = tile[lc + i][dq];
        *(uint4*)(Vt + (long)(d0 + dq) * 16384 + t0 + lc) = *(const uint4*)vals;
    }
}

// One block per row: causal softmax over j<=i, in place on P (bf16).
__global__ __launch_bounds__(256)
void softmax_causal(u16* __restrict__ P)
{
    __shared__ float red[8];
    long rowg = blockIdx.x;              // 0 .. B*N-1
    int i = (int)(rowg & 2047);
    u16* prow = P + (rowg << 11);        // row stride N=2048
    int tid = threadIdx.x;
    int j0 = tid << 3;

    uint4 rv = *(const uint4*)(prow + j0);
    u32 w[4] = {rv.x, rv.y, rv.z, rv.w};
    float x[8];
#pragma unroll
    for (int t = 0; t < 4; ++t) {
        x[2 * t]     = bf16_bits_to_f32(w[t] << 16);
        x[2 * t + 1] = bf16_bits_to_f32(w[t] & 0xffff0000u);
    }
#pragma unroll
    for (int e = 0; e < 8; ++e)
        if (j0 + e > i) x[e] = -1e30f;

    float m = x[0];
#pragma unroll
    for (int e = 1; e < 8; ++e) m = fmaxf(m, x[e]);
#pragma unroll
    for (int o = 32; o; o >>= 1) m = fmaxf(m, __shfl_xor(m, o, 64));
    if ((tid & 63) == 0) red[tid >> 6] = m;
    __syncthreads();
    m = fmaxf(fmaxf(red[0], red[1]), fmaxf(red[2], red[3]));

    float e8[8], s = 0.f;
#pragma unroll
    for (int e = 0; e < 8; ++e) { e8[e] = __expf(x[e] - m); s += e8[e]; }
#pragma unroll
    for (int o = 32; o; o >>= 1) s += __shfl_xor(s, o, 64);
    if ((tid & 63) == 0) red[4 + (tid >> 6)] = s;
    __syncthreads();
    s = red[4] + red[5] + red[6] + red[7];
    float inv = 1.0f / s;

    u32 outw[4];
#pragma unroll
    for (int t = 0; t < 4; ++t) {
        u32 lo = f32_to_bf16(e8[2 * t] * inv);
        u32 hi = f32_to_bf16(e8[2 * t + 1] * inv);
        outw[t] = lo | (hi << 16);
    }
    uint4 ov; ov.x = outw[0]; ov.y = outw[1]; ov.z = outw[2]; ov.w = outw[3];
    *(uint4*)(prow + j0) = ov;
}

extern "C" void kernel_launch(void* const* d_in, const int* in_sizes, int n_in,
                              void* d_out, int out_size, void* d_ws, size_t ws_size,
                              hipStream_t stream)
{
    const int B = 8, N = 2048, D = 1024;
    const long MT = (long)B * N;          // 16384
    const long nX = MT * D;               // 16,777,216
    const long nW = (long)D * D;          // 1,048,576

    const float* x  = (const float*)d_in[0];
    const float* Wq = (const float*)d_in[1];
    const float* Wk = (const float*)d_in[2];
    const float* Wv = (const float*)d_in[3];
    float* out = (float*)d_out;

    // ws layout:
    u16* wb   = (u16*)d_ws;        // [3072][1024] stacked Wq;Wk;Wv
    u16* xb   = wb + 3 * nW;       // [16384][1024]; reused as Vt after QKV gemm
    u16* QKVi = xb + nX;           // [16384][3072] interleaved Q|K|V
    u16* P    = QKVi + 3 * nX;     // [8][2048][2048]
    u16* Vt   = xb;                // alias: [1024][16384]

    // 1) fp32 -> bf16
    cvt_f32_bf16<<<(int)(nX / 1024), 256, 0, stream>>>(x, xb, nX);
    cvt_w3<<<3072, 256, 0, stream>>>(Wq, Wk, Wv, wb);

    // 2) fused QKV projection, XCD-contiguous M-slabs
    qkv_gemm<<<dim3(8, 384, 1), 256, 0, stream>>>(xb, wb, QKVi);

    // 3) V -> Vt (overwrites xb, which is now dead)
    transpose_v<<<dim3(256, 16, 1), 256, 0, stream>>>(QKVi, Vt);

    // 4) S = Q.K^T * 1/32, triangular tiles only, batch -> XCD
    s_gemm<<<dim3(8, 17, 8), 256, 0, stream>>>(QKVi, P);

    // 5) causal softmax in place
    softmax_causal<<<(int)MT, 256, 0, stream>>>(P);

    // 6) O = P.V, K-limited, batch -> XCD
    pv_gemm<<<dim3(8, 8, 16), 256, 0, stream>>>(P, Vt, out);
}

// Round 6
// 420.135 us; speedup vs baseline: 1.1293x; 1.0047x over previous
//
#include <hip/hip_runtime.h>
#include <hip/hip_bf16.h>

#define BM 128
#define BN 128
#define BK 32
#define TILE_ELEMS (BM * BK)   // 4096 u16 = 8 KB

typedef __attribute__((ext_vector_type(4))) float floatx4;
typedef __bf16 bf16x8 __attribute__((ext_vector_type(8)));
typedef unsigned int u32;
typedef unsigned short u16;

typedef __attribute__((address_space(1))) const u32 g_u32;
typedef __attribute__((address_space(3))) u32 l_u32;

__device__ __forceinline__ u16 f32_to_bf16(float f) {
    union { float f; u32 u; } x{f};
    u32 u = x.u;
    u32 r = (u + 0x7fffu + ((u >> 16) & 1u)) >> 16;
    return (u16)r;
}

// Stage a BM x BK (rows x cols) bf16 tile into LDS via global_load_lds width=16.
// LDS layout: row-major [128][32], contiguous (required by global_load_lds).
__device__ __forceinline__ void stage_tile(const u16* gbase, int ld, u16* lds, int tid) {
#pragma unroll
    for (int it = 0; it < 2; ++it) {
        int flat = it * 2048 + tid * 8;       // element index into 128*32 tile
        int row = flat >> 5;                  // /32
        int col = flat & 31;
        const u16* g = gbase + (long)row * ld + col;
        __builtin_amdgcn_global_load_lds((g_u32*)g, (l_u32*)(&lds[flat]), 16, 0, 0);
    }
}

// C[m0+.., n0+..] = scale * sum_k A[m,k] * B[n,k]  (A,B row-major, K-contiguous)
// m97-shape K-loop (dbuf measured slower in R4 — do not re-add).
// MODE 0: plain store (bf16 if OUT_BF16 else fp32)
// MODE 1: score epilogue — store exp(scale*acc) bf16, causal-mask (col>row -> 0),
//         accumulate per-row sums into lsum via 16-lane shuffle + atomicAdd.
// MODE 2: PV epilogue — store fp32 acc * (1/lsum[row]).
template<bool OUT_BF16, int MODE>
__device__ __forceinline__ void gemm_body(
    const u16* __restrict__ Ab, const u16* __restrict__ Bb, void* __restrict__ Cb,
    int lda, int ldb, long ldc, int m0, int n0, int nkt, float scale,
    u16* As, u16* Bs, float* lsum)
{
    int tid = threadIdx.x;

    const u16* Arow = Ab + (long)m0 * lda;
    const u16* Brow = Bb + (long)n0 * ldb;

    stage_tile(Arow, lda, As, tid);
    stage_tile(Brow, ldb, Bs, tid);

    int wave = tid >> 6, lane = tid & 63;
    int wr = (wave >> 1) * 64, wc = (wave & 1) * 64;
    int lrow = lane & 15, quad = lane >> 4;

    floatx4 acc[4][4] = {};
    const int aoff = (wr + lrow) * BK + quad * 8;
    const int boff = (wc + lrow) * BK + quad * 8;

    for (int kt = 0; kt < nkt; ++kt) {
        __syncthreads();   // drains vmcnt: staged tile is in LDS
        bf16x8 af[4], bfr[4];
#pragma unroll
        for (int i = 0; i < 4; ++i) {
            af[i]  = *(const bf16x8*)&As[aoff + i * 16 * BK];
            bfr[i] = *(const bf16x8*)&Bs[boff + i * 16 * BK];
        }
#pragma unroll
        for (int mi = 0; mi < 4; ++mi)
#pragma unroll
            for (int ni = 0; ni < 4; ++ni)
                acc[mi][ni] = __builtin_amdgcn_mfma_f32_16x16x32_bf16(af[mi], bfr[ni], acc[mi][ni], 0, 0, 0);
        __syncthreads();   // all reads done before restage
        if (kt + 1 < nkt) {
            stage_tile(Arow + (kt + 1) * BK, lda, As, tid);
            stage_tile(Brow + (kt + 1) * BK, ldb, Bs, tid);
        }
    }

    // Epilogue: C/D layout col = lane&15, row = quad*4 + r
    long crow0 = m0 + wr + quad * 4;
    int  ccol0 = n0 + wc + lrow;
#pragma unroll
    for (int mi = 0; mi < 4; ++mi) {
#pragma unroll
        for (int r = 0; r < 4; ++r) {
            long row = crow0 + mi * 16 + r;
            float rs = 0.f;
            float linv = 1.f;
            if (MODE == 2) linv = 1.0f / lsum[row];
#pragma unroll
            for (int ni = 0; ni < 4; ++ni) {
                long col = ccol0 + ni * 16;
                float v = acc[mi][ni][r] * scale;
                if (MODE == 1) {
                    // causal: strictly-upper entries (only occur in diagonal
                    // tiles) -> 0. No max-shift: |score| <~ 8, exp safe in fp32.
                    float e = (col > row) ? 0.f : __expf(v);
                    ((u16*)Cb)[row * ldc + col] = f32_to_bf16(e);
                    rs += e;
                } else if (MODE == 2) {
                    ((float*)Cb)[row * ldc + col] = v * linv;
                } else {
                    if (OUT_BF16) ((u16*)Cb)[row * ldc + col] = f32_to_bf16(v);
                    else          ((float*)Cb)[row * ldc + col] = v;
                }
            }
            if (MODE == 1) {
                // reduce over the 16 lanes of this quad-group (cols wc..wc+63)
                rs += __shfl_xor(rs, 1, 16);
                rs += __shfl_xor(rs, 2, 16);
                rs += __shfl_xor(rs, 4, 16);
                rs += __shfl_xor(rs, 8, 16);
                if (lrow == 0) atomicAdd(&lsum[row], rs);
            }
        }
    }
}

// Fused QKV projection: C[16384][3072] = xb[16384][1024] . Wstk[3072][1024]^T
__global__ __launch_bounds__(256)
void qkv_gemm(const u16* __restrict__ A, const u16* __restrict__ B, u16* __restrict__ C)
{
    __shared__ u16 As[TILE_ELEMS];
    __shared__ u16 Bs[TILE_ELEMS];
    int xcd = blockIdx.x, i = blockIdx.y;
    int mt = xcd * 16 + (i & 15);
    int nt = i >> 4;
    gemm_body<true, 0>(A, B, C, 1024, 1024, 3072,
                       mt * BM, nt * BN, 32, 1.0f, As, Bs, nullptr);
}

// Ptilde = exp(Q.K^T / 32) with causal mask, lower-tri tiles only (17x8 fold).
// Row sums accumulate into lsum[b*2048 + row]. blockIdx.x = batch -> XCD.
__global__ __launch_bounds__(256)
void s_gemm(const u16* __restrict__ QKVi, u16* __restrict__ P, float* __restrict__ lsum)
{
    __shared__ u16 As[TILE_ELEMS];
    __shared__ u16 Bs[TILE_ELEMS];
    int b = blockIdx.x, u = blockIdx.y, v = blockIdx.z;
    int mt, nt;
    if (u <= v) { mt = v; nt = u; } else { mt = 15 - v; nt = u - v - 1; }
    const u16* Ab = QKVi + (long)b * 2048 * 3072;        // Q at col 0
    const u16* Bb = Ab + 1024;                            // K at col 1024
    gemm_body<true, 1>(Ab, Bb, P + (long)b * 2048 * 2048, 3072, 3072, 2048,
                       mt * BM, nt * BN, 32, 0.03125f, As, Bs, lsum + b * 2048);
}

// O = (Ptilde.V) / lsum, causal K-limit (Keff = m0+128). blockIdx.x = batch.
__global__ __launch_bounds__(256)
void pv_gemm(const u16* __restrict__ P, const u16* __restrict__ Vt,
             float* __restrict__ O, const float* __restrict__ lsum)
{
    __shared__ u16 As[TILE_ELEMS];
    __shared__ u16 Bs[TILE_ELEMS];
    int b = blockIdx.x, nt = blockIdx.y, mt = blockIdx.z;
    const u16* Ab = P + (long)b * 2048 * 2048;
    const u16* Bb = Vt + (long)b * 2048;                  // ldb = 16384 (all tokens)
    gemm_body<false, 2>(Ab, Bb, O + (long)b * 2048 * 1024, 2048, 16384, 1024,
                        mt * BM, nt * BN, mt * 4 + 4, 1.0f, As, Bs,
                        (float*)lsum + b * 2048);
}

__global__ __launch_bounds__(256)
void cvt_f32_bf16(const float* __restrict__ src, u16* __restrict__ dst, long n)
{
    long idx = ((long)blockIdx.x * 256 + threadIdx.x) << 2;
    if (idx >= n) return;
    float4 f = *(const float4*)(src + idx);
    ushort4 o;
    o.x = f32_to_bf16(f.x); o.y = f32_to_bf16(f.y);
    o.z = f32_to_bf16(f.z); o.w = f32_to_bf16(f.w);
    *(ushort4*)(dst + idx) = o;
}

// Convert all three weight matrices in one launch (1024 blocks/matrix).
__global__ __launch_bounds__(256)
void cvt_w3(const float* __restrict__ Wq, const float* __restrict__ Wk,
            const float* __restrict__ Wv, u16* __restrict__ dst)
{
    int which = blockIdx.x >> 10;
    const float* src = which == 0 ? Wq : (which == 1 ? Wk : Wv);
    long base = (long)(blockIdx.x & 1023) * 1024 + threadIdx.x * 4;
    float4 f = *(const float4*)(src + base);
    ushort4 o;
    o.x = f32_to_bf16(f.x); o.y = f32_to_bf16(f.y);
    o.z = f32_to_bf16(f.z); o.w = f32_to_bf16(f.w);
    *(ushort4*)(dst + (long)which * 1048576 + base) = o;
}

// Transpose V slice of QKVi (cols 2048..3071) -> Vt[1024][16384], 64x64 LDS tiles.
__global__ __launch_bounds__(256)
void transpose_v(const u16* __restrict__ QKVi, u16* __restrict__ Vt)
{
    __shared__ u16 tile[64][64 + 8];
    int t0 = blockIdx.x * 64;            // token tile (256)
    int d0 = blockIdx.y * 64;            // dv tile (16)
    int tid = threadIdx.x;
    int lr = tid >> 3, lc = (tid & 7) * 8;
#pragma unroll
    for (int p = 0; p < 2; ++p) {
        int tok = lr + p * 32;
        const u16* src = QKVi + (long)(t0 + tok) * 3072 + 2048 + d0 + lc;
        *(uint4*)&tile[tok][lc] = *(const uint4*)src;
    }
    __syncthreads();
#pragma unroll
    for (int p = 0; p < 2; ++p) {
        int dq = lr + p * 32;
        u16 vals[8];
#pragma unroll
        for (int i = 0; i < 8; ++i) vals[i] = tile[lc + i][dq];
        *(uint4*)(Vt + (long)(d0 + dq) * 16384 + t0 + lc) = *(const uint4*)vals;
    }
}

extern "C" void kernel_launch(void* const* d_in, const int* in_sizes, int n_in,
                              void* d_out, int out_size, void* d_ws, size_t ws_size,
                              hipStream_t stream)
{
    const int B = 8, N = 2048, D = 1024;
    const long MT = (long)B * N;          // 16384
    const long nX = MT * D;               // 16,777,216
    const long nW = (long)D * D;          // 1,048,576

    const float* x  = (const float*)d_in[0];
    const float* Wq = (const float*)d_in[1];
    const float* Wk = (const float*)d_in[2];
    const float* Wv = (const float*)d_in[3];
    float* out = (float*)d_out;

    // ws layout:
    u16* wb   = (u16*)d_ws;        // [3072][1024] stacked Wq;Wk;Wv; dead after qkv
    u16* xb   = wb + 3 * nW;       // [16384][1024]; reused as Vt after QKV gemm
    u16* QKVi = xb + nX;           // [16384][3072] interleaved Q|K|V
    u16* P    = QKVi + 3 * nX;     // [8][2048][2048] exp(scores), unnormalized
    u16* Vt   = xb;                // alias: [1024][16384]
    float* lsum = (float*)wb;      // alias: [8][2048] row sums (wb dead after qkv)

    // 1) fp32 -> bf16
    cvt_f32_bf16<<<(int)(nX / 1024), 256, 0, stream>>>(x, xb, nX);
    cvt_w3<<<3072, 256, 0, stream>>>(Wq, Wk, Wv, wb);

    // 2) fused QKV projection
    qkv_gemm<<<dim3(8, 384, 1), 256, 0, stream>>>(xb, wb, QKVi);

    // 3) zero row-sum accumulator (wb now dead); V -> Vt (xb now dead)
    hipMemsetAsync(lsum, 0, (size_t)B * N * sizeof(float), stream);
    transpose_v<<<dim3(256, 16, 1), 256, 0, stream>>>(QKVi, Vt);

    // 4) Ptilde = exp(Q.K^T/32) masked, + row sums. Triangular tiles only.
    s_gemm<<<dim3(8, 17, 8), 256, 0, stream>>>(QKVi, P, lsum);

    // 5) O = Ptilde.V / lsum, K-limited
    pv_gemm<<<dim3(8, 8, 16), 256, 0, stream>>>(P, Vt, out, lsum);
}